// Round 8
// baseline (256.800 us; speedup 1.0000x reference)
//
#include <hip/hip_runtime.h>

// ---- problem constants ----
#define D_MODEL 1024
#define NHEAD   16
#define DK      64
#define BATCH   2
#define SEQ     2048

typedef __attribute__((ext_vector_type(8))) short bf16x8;
typedef __attribute__((ext_vector_type(4))) float f32x4;
typedef __attribute__((ext_vector_type(16))) float f32x16;
typedef __attribute__((ext_vector_type(4))) int i32x4;

#define QSCALE 0.18033688011f   // log2(e) / sqrt(64): folded into Q projection

__device__ __forceinline__ unsigned short f2b(float x) {
  unsigned u = __builtin_bit_cast(unsigned, x);
  u = (u + 0x7fffu + ((u >> 16) & 1u)) >> 16;   // RNE to bf16
  return (unsigned short)u;
}
// round-half-up bf16 (bias 2^-17 rel, error <= 2^-9 like RNE) -- 1 add
__device__ __forceinline__ unsigned short f2b_rhu(float x) {
  return (unsigned short)((__builtin_bit_cast(unsigned, x) + 0x8000u) >> 16);
}
// pack two fp32 -> two bf16 (round-half-up) in 3 VALU: add, add, v_perm
__device__ __forceinline__ int pk2(float a, float b) {
  unsigned ua = __builtin_bit_cast(unsigned, a) + 0x8000u;
  unsigned ub = __builtin_bit_cast(unsigned, b) + 0x8000u;
  return (int)__builtin_amdgcn_perm(ub, ua, 0x07060302u);  // [ub.hi16 : ua.hi16]
}
// same on raw (already-masked) fp32 bit patterns (R2-proven)
__device__ __forceinline__ int pk2u(unsigned ua, unsigned ub) {
  return (int)__builtin_amdgcn_perm(ub + 0x8000u, ua + 0x8000u, 0x07060302u);
}

// async 16B global->LDS (m97 pattern). LDS dest = wave-uniform base + lane*16.
typedef const __attribute__((address_space(1))) void* gas_p;
typedef __attribute__((address_space(3))) void* las_p;
__device__ __forceinline__ void gll16(const void* g, void* l) {
  __builtin_amdgcn_global_load_lds((gas_p)g, (las_p)l, 16, 0, 0);
}

// 32x32x16 bf16 MFMA. C layout (m74/m101-verified): col=l&31,
// row=(reg&3)+8*(reg>>2)+4*(l>>5). A/B: row/col=l&31; the slot->k mapping
// cancels between A and B as long as both use the same slot->key convention.
__device__ __forceinline__ f32x16 mfma32(bf16x8 a, bf16x8 b, f32x16 c) {
  return __builtin_amdgcn_mfma_f32_32x32x16_bf16(a, b, c, 0, 0, 0);
}

// ---- fused preprocessing: cast3 + wtrans + maskpack in ONE launch ----
__global__ __launch_bounds__(256) void prep_kernel(
    const float* __restrict__ q, const float* __restrict__ k, const float* __restrict__ v,
    unsigned short* __restrict__ qb, unsigned short* __restrict__ kb,
    unsigned short* __restrict__ vb,
    const float* __restrict__ wq, const float* __restrict__ wk,
    const float* __restrict__ wv, const float* __restrict__ wf,
    unsigned short* __restrict__ wqt, unsigned short* __restrict__ wkt,
    unsigned short* __restrict__ wvt, unsigned short* __restrict__ wft,
    const int* __restrict__ mask, unsigned long long* __restrict__ mbits) {
  int bid = blockIdx.x, t = threadIdx.x;
  if (bid < 6144) {
    int by = bid >> 11, bx = bid & 2047;
    const float* src = by == 0 ? q : (by == 1 ? k : v);
    unsigned short* dst = by == 0 ? qb : (by == 1 ? kb : vb);
    size_t i = ((size_t)bx * 256 + t) * 8;
    float4 x0 = *(const float4*)&src[i];
    float4 x1 = *(const float4*)&src[i + 4];
    int4 w;
    w.x = pk2(x0.x, x0.y); w.y = pk2(x0.z, x0.w);
    w.z = pk2(x1.x, x1.y); w.w = pk2(x1.z, x1.w);
    *(int4*)&dst[i] = w;
  } else if (bid < 7168) {
    __shared__ float tile[64][65];
    int idx = bid - 6144;
    int bz = idx >> 8, by = (idx >> 4) & 15, bx = idx & 15;
    const float* w; unsigned short* wt;
    switch (bz) {
      case 0: w = wq; wt = wqt; break;
      case 1: w = wk; wt = wkt; break;
      case 2: w = wv; wt = wvt; break;
      default: w = wf; wt = wft; break;
    }
    int r0 = by * 64, c0 = bx * 64;
    for (int i = 0; i < 16; ++i) {
      int idx2 = t + i * 256; int r = idx2 >> 6, c = idx2 & 63;
      tile[r][c] = w[(size_t)(r0 + r) * D_MODEL + c0 + c];
    }
    __syncthreads();
    for (int i = 0; i < 16; ++i) {
      int idx2 = t + i * 256; int r = idx2 >> 6, c = idx2 & 63;
      wt[(size_t)(c0 + r) * D_MODEL + r0 + c] = f2b(tile[c][r]);
    }
  } else {
    int idx = bid - 7168;             // [0, 8192)
    int lane = t & 63, wave = t >> 6;
    size_t base = ((size_t)idx * 4 + wave) * 256;   // 256 keys per wave
    unsigned long long b0 = __ballot(mask[base + lane] != 0);
    unsigned long long b1 = __ballot(mask[base + 64 + lane] != 0);
    unsigned long long b2 = __ballot(mask[base + 128 + lane] != 0);
    unsigned long long b3 = __ballot(mask[base + 192 + lane] != 0);
    if (lane == 0) {
      unsigned long long* p = &mbits[(size_t)idx * 16 + wave * 4];
      p[0] = b0; p[1] = b1; p[2] = b2; p[3] = b3;
    }
  }
}

// ---- fused QKV projection GEMM: 128x128 tile, BK=32, double-buffered,
// one barrier per iteration; LDS-staged coalesced epilogues.
// V epilogue stores keys PERMUTED within each 16-group (quad 1<->2 swap) so
// the attention PV B-operand slot order matches the S^T C-layout's native
// per-lane key order (no cross-lane P exchange needed in attention). ----
__global__ __launch_bounds__(256) void gemm_qkv_kernel(
    const unsigned short* __restrict__ qb, const unsigned short* __restrict__ kb,
    const unsigned short* __restrict__ vb,
    const unsigned short* __restrict__ wqt, const unsigned short* __restrict__ wkt,
    const unsigned short* __restrict__ wvt,
    const float* __restrict__ bq, const float* __restrict__ bv,
    unsigned short* __restrict__ qh, unsigned short* __restrict__ kh,
    unsigned short* __restrict__ vt) {
  __shared__ unsigned short SB[16640];
  int bid = blockIdx.x;
  int xcd = bid & 7, slot = bid >> 3;      // 96 slots per XCD
  int mi = slot & 3, zn = slot >> 2;       // 4 m-panels per XCD, zn in [0,24)
  int z = zn >> 3;
  int n0 = (zn & 7) * 128;
  int m0 = (mi * 8 + xcd) * 128;
  const unsigned short* A; const unsigned short* Bt;
  switch (z) {
    case 0:  A = qb; Bt = wqt; break;
    case 1:  A = kb; Bt = wkt; break;
    default: A = vb; Bt = wvt; break;
  }
  int t = threadIdx.x, lane = t & 63, wave = t >> 6;
  int l16 = lane & 15, quad = lane >> 4;
  int wm = (wave & 1) * 64, wn = (wave >> 1) * 64;
  f32x4 zero = {0.f, 0.f, 0.f, 0.f};
  f32x4 acc[4][4];
  for (int mt = 0; mt < 4; ++mt) for (int nt = 0; nt < 4; ++nt) acc[mt][nt] = zero;

  int drow = lane >> 2, dcol = (lane & 3) * 8;
  const unsigned short* asrc = A  + (size_t)(m0 + wave * 32 + drow) * D_MODEL + dcol;
  const unsigned short* bsrc = Bt + (size_t)(n0 + wave * 32 + drow) * D_MODEL + dcol;
  int dst = wave * 1024 + lane * 8;        // within-buffer wave slice (+g*512)

#pragma unroll
  for (int g = 0; g < 2; ++g) {
    gll16(asrc + (size_t)(g * 16) * D_MODEL, &SB[dst + g * 512]);
    gll16(bsrc + (size_t)(g * 16) * D_MODEL, &SB[4096 + dst + g * 512]);
  }
  for (int it = 0; it < 32; ++it) {
    __syncthreads();
    if (it + 1 < 32) {
      int nb = ((it + 1) & 1) * 8192, kn = (it + 1) * 32;
#pragma unroll
      for (int g = 0; g < 2; ++g) {
        gll16(asrc + (size_t)(g * 16) * D_MODEL + kn, &SB[nb + dst + g * 512]);
        gll16(bsrc + (size_t)(g * 16) * D_MODEL + kn, &SB[nb + 4096 + dst + g * 512]);
      }
    }
    int cb = (it & 1) * 8192;
    bf16x8 a[4], b[4];
    for (int mt = 0; mt < 4; ++mt)
      a[mt] = *(const bf16x8*)&SB[cb + (wm + mt * 16 + l16) * 32 + quad * 8];
    for (int nt = 0; nt < 4; ++nt)
      b[nt] = *(const bf16x8*)&SB[cb + 4096 + (wn + nt * 16 + l16) * 32 + quad * 8];
    for (int mt = 0; mt < 4; ++mt)
      for (int nt = 0; nt < 4; ++nt)
        acc[mt][nt] = __builtin_amdgcn_mfma_f32_16x16x32_bf16(a[mt], b[nt], acc[mt][nt], 0, 0, 0);
  }

  if (z == 2) {
    __syncthreads();
    // key-permuted store: within each 16-key group, s-position = key with
    // bits 2<->3 swapped == quad 1<->2 swap (self-inverse).
    int qs = ((quad & 1) << 1) | (quad >> 1);
#pragma unroll
    for (int nt = 0; nt < 4; ++nt) {
      int col = wn + nt * 16 + l16;
      float bb = bv[n0 + col];
      for (int mt = 0; mt < 4; ++mt)
        for (int r = 0; r < 4; ++r)
          SB[col * 130 + wm + mt * 16 + qs * 4 + r] = f2b_rhu(acc[mt][nt][r] + bb);
    }
    __syncthreads();
    int c = t >> 1, hf = t & 1;
    int colg = n0 + c, hh = colg >> 6, dd = colg & 63;
    int b_ = m0 >> 11, sbase = m0 & (SEQ - 1);
    unsigned short* dstp = vt + (((size_t)(b_ * NHEAD + hh)) * DK + dd) * SEQ + sbase + hf * 64;
#pragma unroll
    for (int j = 0; j < 8; ++j)
      *(int4*)(dstp + j * 8) = *(const int4*)&SB[c * 130 + hf * 64 + j * 8];
  } else {
    __syncthreads();
#pragma unroll
    for (int nt = 0; nt < 4; ++nt) {
      int lcol = wn + nt * 16 + l16;
      float bb = (z == 0) ? bq[n0 + lcol] : 0.f;
      for (int mt = 0; mt < 4; ++mt)
        for (int r = 0; r < 4; ++r) {
          float val = acc[mt][nt][r] + bb;
          if (z == 0) val *= QSCALE;
          SB[(wm + mt * 16 + quad * 4 + r) * 130 + lcol] = f2b_rhu(val);
        }
    }
    __syncthreads();
    unsigned short* outp = (z == 0) ? qh : kh;
    int b_ = m0 >> 11, sbase = m0 & (SEQ - 1);
    int h0 = n0 >> 6, c = t & 7;
#pragma unroll
    for (int pass = 0; pass < 8; ++pass) {
      int rp = pass * 32 + (t >> 3);
      int srow = rp >> 1, part = rp & 1;
      unsigned short* dstp = outp +
          (((size_t)(b_ * NHEAD + h0 + part)) * SEQ + sbase + srow) * DK + c * 8;
      *(int4*)dstp = *(const int4*)&SB[srow * 130 + part * 64 + c * 8];
    }
  }
}

// ---- output projection GEMM: 64x64 tiles, BK=64 double-buffered ----
__global__ __launch_bounds__(256) void gemm_out_kernel(
    const unsigned short* __restrict__ A, const unsigned short* __restrict__ Bt,
    const float* __restrict__ bias, float* __restrict__ out) {
  __shared__ unsigned short As[8192], Bs[8192];
  int bid = blockIdx.x;
  int xcd = bid & 7, slot = bid >> 3;
  int mi = slot & 7, n0 = (slot >> 3) * 64;
  int m0 = (mi * 8 + xcd) * 64;
  int t = threadIdx.x, lane = t & 63, wave = t >> 6;
  int l16 = lane & 15, quad = lane >> 4;
  int wm = (wave & 1) * 32, wn = (wave >> 1) * 32;
  f32x4 zero = {0.f, 0.f, 0.f, 0.f};
  f32x4 acc[2][2];
  for (int mt = 0; mt < 2; ++mt) for (int nt = 0; nt < 2; ++nt) acc[mt][nt] = zero;

  int drow = lane >> 2, dcol = (lane & 3) * 8;
  const unsigned short* asrc = A  + (size_t)(m0 + wave * 16 + drow) * D_MODEL + dcol;
  const unsigned short* bsrc = Bt + (size_t)(n0 + wave * 16 + drow) * D_MODEL + dcol;
  int dst = wave * 512 + lane * 8;

#pragma unroll
  for (int hf = 0; hf < 2; ++hf) {
    gll16(asrc + hf * 32, &As[dst + hf * 2048]);
    gll16(bsrc + hf * 32, &Bs[dst + hf * 2048]);
  }
  for (int it = 0; it < 16; ++it) {
    __syncthreads();
    if (it + 1 < 16) {
      int nb = ((it + 1) & 1) * 4096, kn = (it + 1) * 64;
#pragma unroll
      for (int hf = 0; hf < 2; ++hf) {
        gll16(asrc + kn + hf * 32, &As[nb + dst + hf * 2048]);
        gll16(bsrc + kn + hf * 32, &Bs[nb + dst + hf * 2048]);
      }
    }
    int cb = (it & 1) * 4096;
#pragma unroll
    for (int half = 0; half < 2; ++half) {
      bf16x8 a[2], b[2];
      for (int mt = 0; mt < 2; ++mt)
        a[mt] = *(const bf16x8*)&As[cb + half * 2048 + (wm + mt * 16 + l16) * 32 + quad * 8];
      for (int nt = 0; nt < 2; ++nt)
        b[nt] = *(const bf16x8*)&Bs[cb + half * 2048 + (wn + nt * 16 + l16) * 32 + quad * 8];
      for (int mt = 0; mt < 2; ++mt)
        for (int nt = 0; nt < 2; ++nt)
          acc[mt][nt] = __builtin_amdgcn_mfma_f32_16x16x32_bf16(a[mt], b[nt], acc[mt][nt], 0, 0, 0);
    }
  }
  for (int nt = 0; nt < 2; ++nt) {
    int col = n0 + wn + nt * 16 + l16;
    float bb = bias[col];
    for (int mt = 0; mt < 2; ++mt)
      for (int r = 0; r < 4; ++r) {
        int row = m0 + wm + mt * 16 + quad * 4 + r;
        out[(size_t)row * D_MODEL + col] = acc[mt][nt][r] + bb;
      }
  }
}

// ---- flash attention R17: 32x32 core + kt software pipeline (T15) ----
// R7 counters (MfmaUtil 26, VALUBusy 44, conflicts tiny, HBM 4.5%, occ 17)
// = latency-bound: S-MFMA -> softmax-VALU -> PV-MFMA run strictly serial per
// kt with only 2 waves/SIMD to fill bubbles. Fix: rolling 2-accumulator
// pipeline -- the S-MFMA cluster for kt+1 (pure MFMA+LDS work) issues BEFORE
// softmax(kt)'s ~88 VALU ops, so matrix and vector pipes overlap within the
// wave. Fully-unrolled kt with named sA/sB (no dynamic indexing, rule #20).
// Numerics/layout identical to R7 (all ops proven).
__global__ __launch_bounds__(256, 2) void attn_kernel(
    const unsigned short* __restrict__ qh, const unsigned short* __restrict__ kh,
    const unsigned short* __restrict__ vt, const unsigned long long* __restrict__ mbits,
    unsigned short* __restrict__ attb) {
  __shared__ unsigned short Ks[16384];  // 2 bufs x [128 k-rows][64 d], swizzled
  __shared__ unsigned short Vs[16384];  // 2 bufs x [64 d-rows][128 s], swizzled
  int bid = blockIdx.x;
  int xcd = bid & 7, slot = bid >> 3;   // 64 slots per XCD
  int bh_ = 4 * xcd + (slot >> 4);      // 4 bh per XCD (KV L2 locality)
  int qt = slot & 15;                   // 16 q-tiles of 128 rows
  int b = bh_ >> 4, h = bh_ & 15;
  int t = threadIdx.x, lane = t & 63, wave = t >> 6;   // 4 waves
  int l32 = lane & 31, hi = lane >> 5;
  size_t bh = (size_t)b * NHEAD + h;

  const unsigned short* Kg = kh + bh * SEQ * DK;
  const unsigned short* Vg = vt + bh * DK * SEQ;
  const unsigned long long* mrow = mbits + (size_t)b * SEQ * (SEQ / 64);
  int qrowb = qt * 128 + wave * 32;     // this wave's 32 q-rows

  // Q fragments (B-operand: col=q=l32, slot (hi,j) -> d = step*16 + hi*8 + j)
  bf16x8 qf[4];
  {
    const unsigned short* Qg = qh + (bh * SEQ + (size_t)(qrowb + l32)) * DK;
#pragma unroll
    for (int step = 0; step < 4; ++step)
      qf[step] = *(const bf16x8*)&Qg[(step * 2 + hi) * 8];
  }

  // K staging: 4 gll16/tile, each 32 rows x 8 chunks (row = t>>3)
  int ksrow = t >> 3;
  int kschk = ((t & 7) ^ (ksrow & 7)) * 8;
  const unsigned short* ksrc = Kg + (size_t)ksrow * DK + kschk;
  // V staging: 4 gll16/tile, each 16 rows x 16 chunks (row = t>>4)
  int vsrow = t >> 4;
  int vschk = ((t & 15) ^ (vsrow & 15)) * 8;
  const unsigned short* vsrc = Vg + (size_t)vsrow * SEQ + vschk;
  int sdst = t * 8;                     // + g*2048 shorts per call

  // K read bases: row = l32 (+kt*32), d-chunk = 2*step + hi, XOR row&7
  int kx = l32 & 7;
  int kaddr[4];
#pragma unroll
  for (int step = 0; step < 4; ++step)
    kaddr[step] = l32 * 64 + (((step * 2 + hi) ^ kx) * 8);
  // V read: row = l32 (+32 for accO1), s-chunk = kt*4 + kstep*2 + hi, XOR row&15
  int vx = l32 & 15;

  size_t mi0 = (size_t)(qrowb + l32) * (SEQ / 64);

  bf16x8 ones8;
#pragma unroll
  for (int i = 0; i < 8; ++i) ones8[i] = (short)0x3F80;

  f32x16 zero16;
#pragma unroll
  for (int i = 0; i < 16; ++i) zero16[i] = 0.f;
  f32x16 accO0 = zero16, accO1 = zero16, accRS = zero16;

  // prologue: K(0), V(0) -> buf0
#pragma unroll
  for (int g = 0; g < 4; ++g) {
    gll16(ksrc + (size_t)(g * 32) * DK, &Ks[g * 2048 + sdst]);
    gll16(vsrc + (size_t)(g * 16) * SEQ, &Vs[g * 2048 + sdst]);
  }

  for (int tk = 0; tk < SEQ / 128; ++tk) {
    __syncthreads();   // drains K(tk)+V(tk), issued a full compute phase ago
    if (tk + 1 < SEQ / 128) {
      int nb = ((tk + 1) & 1) * 8192;
      const unsigned short* kn = ksrc + (size_t)(tk + 1) * 128 * DK;
      const unsigned short* vn = vsrc + (tk + 1) * 128;
#pragma unroll
      for (int g = 0; g < 4; ++g) {
        gll16(kn + (size_t)(g * 32) * DK, &Ks[nb + g * 2048 + sdst]);
        gll16(vn + (size_t)(g * 16) * SEQ, &Vs[nb + g * 2048 + sdst]);
      }
    }
    // mask words issued early (S-MFMA hides their latency)
    unsigned long long m0 = mrow[mi0 + 2 * tk];
    unsigned long long m1 = mrow[mi0 + 2 * tk + 1];

    int cb = (tk & 1) * 8192;

    // pipeline prologue: S(kt=0)
    f32x16 sA = zero16;
    __builtin_amdgcn_s_setprio(1);
#pragma unroll
    for (int step = 0; step < 4; ++step) {
      bf16x8 kf = *(const bf16x8*)&Ks[cb + kaddr[step]];
      sA = mfma32(kf, qf[step], sA);
    }
    __builtin_amdgcn_s_setprio(0);

#pragma unroll
    for (int kt = 0; kt < 4; ++kt) {
      // issue S(kt+1) MFMAs FIRST -- they run on the matrix pipe while the
      // softmax VALU below processes sA (already complete).
      f32x16 sB = zero16;
      if (kt < 3) {
        __builtin_amdgcn_s_setprio(1);
#pragma unroll
        for (int step = 0; step < 4; ++step) {
          bf16x8 kf = *(const bf16x8*)&Ks[cb + (kt + 1) * 2048 + kaddr[step]];
          sB = mfma32(kf, qf[step], sB);
        }
        __builtin_amdgcn_s_setprio(0);
      }

      // masked p = exp2(sA) (bit pos = (r&3)+8*(r>>2) in the 4hi-shifted word)
      unsigned wk_ = (unsigned)(((kt < 2) ? m0 : m1) >> ((kt & 1) * 32));
      unsigned w = wk_ >> (4 * hi);
      unsigned pu[16];
#pragma unroll
      for (int r = 0; r < 16; ++r) {
        float pv = __builtin_amdgcn_exp2f(sA[r]);
        const int pos = (r & 3) + 8 * (r >> 2);
        int msk = ((int)(w << (31 - pos))) >> 31;
        pu[r] = __builtin_bit_cast(unsigned, pv) & (unsigned)msk;
      }
      // PV A-frags: OWN regs in order. Slot (hi,j) -> key 4hi+(j&3)+8*(j>>2);
      // V storage is permuted to the identical slot order (gemm_qkv quad-swap).
      i32x4 w0v = {pk2u(pu[0], pu[1]),  pk2u(pu[2], pu[3]),
                   pk2u(pu[4], pu[5]),  pk2u(pu[6], pu[7])};    // keys [0,16)
      i32x4 w1v = {pk2u(pu[8], pu[9]),  pk2u(pu[10], pu[11]),
                   pk2u(pu[12], pu[13]), pk2u(pu[14], pu[15])}; // keys [16,32)
      bf16x8 ap0 = __builtin_bit_cast(bf16x8, w0v);
      bf16x8 ap1 = __builtin_bit_cast(bf16x8, w1v);

      __builtin_amdgcn_s_setprio(1);
      // row sums on MFMA pipe (ones = permutation-invariant)
      accRS = mfma32(ap0, ones8, accRS);
      accRS = mfma32(ap1, ones8, accRS);
      // O += P V : B slot (hi,j) reads permuted position kt*32+kstep*16+hi*8+j
      {
        int c0 = ((kt * 4 + hi) ^ vx) * 8;        // kstep0 chunk
        int c1 = ((kt * 4 + 2 + hi) ^ vx) * 8;    // kstep1 chunk
        bf16x8 vf00 = *(const bf16x8*)&Vs[cb + l32 * 128 + c0];
        bf16x8 vf01 = *(const bf16x8*)&Vs[cb + 4096 + l32 * 128 + c0];
        bf16x8 vf10 = *(const bf16x8*)&Vs[cb + l32 * 128 + c1];
        bf16x8 vf11 = *(const bf16x8*)&Vs[cb + 4096 + l32 * 128 + c1];
        accO0 = mfma32(ap0, vf00, accO0);
        accO1 = mfma32(ap0, vf01, accO1);
        accO0 = mfma32(ap1, vf10, accO0);
        accO1 = mfma32(ap1, vf11, accO1);
      }
      __builtin_amdgcn_s_setprio(0);

      sA = sB;   // rolling accumulator (SSA-renamed after full unroll)
    }
  }

  // epilogue: lane holds O[q at regs][d = l32 (+32)]; RS same reg-q layout
#pragma unroll
  for (int r = 0; r < 16; ++r) {
    float sden = accRS[r];
    float inv = sden > 0.f ? 1.f / sden : 0.f;
    int qq = (r & 3) + 8 * (r >> 2) + 4 * hi;
    int row = qrowb + qq;
    size_t ob = ((size_t)b * SEQ + row) * D_MODEL + (size_t)h * DK + l32;
    attb[ob] = f2b_rhu(accO0[r] * inv);
    attb[ob + 32] = f2b_rhu(accO1[r] * inv);
  }
}

extern "C" void kernel_launch(void* const* d_in, const int* in_sizes, int n_in,
                              void* d_out, int out_size, void* d_ws, size_t ws_size,
                              hipStream_t stream) {
  (void)in_sizes; (void)n_in; (void)out_size; (void)ws_size;
  const float* q    = (const float*)d_in[0];
  const float* k    = (const float*)d_in[1];
  const float* v    = (const float*)d_in[2];
  const int*   mask = (const int*)d_in[3];
  const float* wq   = (const float*)d_in[4];
  const float* bq   = (const float*)d_in[5];
  const float* wk   = (const float*)d_in[6];
  const float* wv   = (const float*)d_in[7];
  const float* bv   = (const float*)d_in[8];
  const float* wf   = (const float*)d_in[9];
  const float* bf   = (const float*)d_in[10];

  char* ws = (char*)d_ws;
  unsigned short* wft  = (unsigned short*)(ws + 0);          // 2 MiB, live till end
  unsigned short* wqt  = (unsigned short*)(ws + 2097152);    // 2 MiB
  unsigned short* wkt  = (unsigned short*)(ws + 4194304);    // 2 MiB
  unsigned short* wvt  = (unsigned short*)(ws + 6291456);    // 2 MiB
  unsigned short* attb = (unsigned short*)(ws + 2097152);    // 8 MiB alias
  unsigned short* qhp  = (unsigned short*)(ws + 10485760);   // 8 MiB
  unsigned short* khp  = (unsigned short*)(ws + 18874368);   // 8 MiB
  unsigned short* vtp  = (unsigned short*)(ws + 27262976);   // 8 MiB
  unsigned long long* mbits = (unsigned long long*)(ws + 35651584); // 1 MiB
  unsigned short* vb   = (unsigned short*)(ws + 36700160);   // 8 MiB
  unsigned short* qb   = (unsigned short*)d_out;             // 8 MiB (d_out scratch)
  unsigned short* kb   = (unsigned short*)d_out + 4194304;   // 8 MiB

  hipLaunchKernelGGL(prep_kernel, dim3(15360), dim3(256), 0, stream,
                     q, k, v, qb, kb, vb,
                     wq, wk, wv, wf, wqt, wkt, wvt, wft, mask, mbits);
  hipLaunchKernelGGL(gemm_qkv_kernel, dim3(768), dim3(256), 0, stream,
                     qb, kb, vb, wqt, wkt, wvt, bq, bv, qhp, khp, vtp);
  hipLaunchKernelGGL(attn_kernel, dim3(512), dim3(256), 0, stream,
                     qhp, khp, vtp, mbits, attb);
  hipLaunchKernelGGL(gemm_out_kernel, dim3(1024), dim3(256), 0, stream,
                     attb, wft, bf, (float*)d_out);
}

// Round 9
// 247.243 us; speedup vs baseline: 1.0387x; 1.0387x over previous
//
#include <hip/hip_runtime.h>

// ---- problem constants ----
#define D_MODEL 1024
#define NHEAD   16
#define DK      64
#define BATCH   2
#define SEQ     2048

typedef __attribute__((ext_vector_type(8))) short bf16x8;
typedef __attribute__((ext_vector_type(4))) float f32x4;
typedef __attribute__((ext_vector_type(16))) float f32x16;
typedef __attribute__((ext_vector_type(4))) int i32x4;

#define QSCALE 0.18033688011f   // log2(e) / sqrt(64): folded into Q projection

__device__ __forceinline__ unsigned short f2b(float x) {
  unsigned u = __builtin_bit_cast(unsigned, x);
  u = (u + 0x7fffu + ((u >> 16) & 1u)) >> 16;   // RNE to bf16
  return (unsigned short)u;
}
// round-half-up bf16 (bias 2^-17 rel, error <= 2^-9 like RNE) -- 1 add
__device__ __forceinline__ unsigned short f2b_rhu(float x) {
  return (unsigned short)((__builtin_bit_cast(unsigned, x) + 0x8000u) >> 16);
}
// pack two fp32 -> two bf16 (round-half-up) in 3 VALU: add, add, v_perm
__device__ __forceinline__ int pk2(float a, float b) {
  unsigned ua = __builtin_bit_cast(unsigned, a) + 0x8000u;
  unsigned ub = __builtin_bit_cast(unsigned, b) + 0x8000u;
  return (int)__builtin_amdgcn_perm(ub, ua, 0x07060302u);  // [ub.hi16 : ua.hi16]
}
// same on raw (already-masked) fp32 bit patterns (R2-proven)
__device__ __forceinline__ int pk2u(unsigned ua, unsigned ub) {
  return (int)__builtin_amdgcn_perm(ub + 0x8000u, ua + 0x8000u, 0x07060302u);
}

// async 16B global->LDS (m97 pattern). LDS dest = wave-uniform base + lane*16.
typedef const __attribute__((address_space(1))) void* gas_p;
typedef __attribute__((address_space(3))) void* las_p;
__device__ __forceinline__ void gll16(const void* g, void* l) {
  __builtin_amdgcn_global_load_lds((gas_p)g, (las_p)l, 16, 0, 0);
}

// 32x32x16 bf16 MFMA. C layout (m74/m101-verified): col=l&31,
// row=(reg&3)+8*(reg>>2)+4*(l>>5). A/B: row/col=l&31; the slot->k mapping
// cancels between A and B as long as both use the same slot->key convention.
__device__ __forceinline__ f32x16 mfma32(bf16x8 a, bf16x8 b, f32x16 c) {
  return __builtin_amdgcn_mfma_f32_32x32x16_bf16(a, b, c, 0, 0, 0);
}

// ---- fused preprocessing: cast3 + wtrans + maskpack in ONE launch ----
__global__ __launch_bounds__(256) void prep_kernel(
    const float* __restrict__ q, const float* __restrict__ k, const float* __restrict__ v,
    unsigned short* __restrict__ qb, unsigned short* __restrict__ kb,
    unsigned short* __restrict__ vb,
    const float* __restrict__ wq, const float* __restrict__ wk,
    const float* __restrict__ wv, const float* __restrict__ wf,
    unsigned short* __restrict__ wqt, unsigned short* __restrict__ wkt,
    unsigned short* __restrict__ wvt, unsigned short* __restrict__ wft,
    const int* __restrict__ mask, unsigned long long* __restrict__ mbits) {
  int bid = blockIdx.x, t = threadIdx.x;
  if (bid < 6144) {
    int by = bid >> 11, bx = bid & 2047;
    const float* src = by == 0 ? q : (by == 1 ? k : v);
    unsigned short* dst = by == 0 ? qb : (by == 1 ? kb : vb);
    size_t i = ((size_t)bx * 256 + t) * 8;
    float4 x0 = *(const float4*)&src[i];
    float4 x1 = *(const float4*)&src[i + 4];
    int4 w;
    w.x = pk2(x0.x, x0.y); w.y = pk2(x0.z, x0.w);
    w.z = pk2(x1.x, x1.y); w.w = pk2(x1.z, x1.w);
    *(int4*)&dst[i] = w;
  } else if (bid < 7168) {
    __shared__ float tile[64][65];
    int idx = bid - 6144;
    int bz = idx >> 8, by = (idx >> 4) & 15, bx = idx & 15;
    const float* w; unsigned short* wt;
    switch (bz) {
      case 0: w = wq; wt = wqt; break;
      case 1: w = wk; wt = wkt; break;
      case 2: w = wv; wt = wvt; break;
      default: w = wf; wt = wft; break;
    }
    int r0 = by * 64, c0 = bx * 64;
    for (int i = 0; i < 16; ++i) {
      int idx2 = t + i * 256; int r = idx2 >> 6, c = idx2 & 63;
      tile[r][c] = w[(size_t)(r0 + r) * D_MODEL + c0 + c];
    }
    __syncthreads();
    for (int i = 0; i < 16; ++i) {
      int idx2 = t + i * 256; int r = idx2 >> 6, c = idx2 & 63;
      wt[(size_t)(c0 + r) * D_MODEL + r0 + c] = f2b(tile[c][r]);
    }
  } else {
    int idx = bid - 7168;             // [0, 8192)
    int lane = t & 63, wave = t >> 6;
    size_t base = ((size_t)idx * 4 + wave) * 256;   // 256 keys per wave
    unsigned long long b0 = __ballot(mask[base + lane] != 0);
    unsigned long long b1 = __ballot(mask[base + 64 + lane] != 0);
    unsigned long long b2 = __ballot(mask[base + 128 + lane] != 0);
    unsigned long long b3 = __ballot(mask[base + 192 + lane] != 0);
    if (lane == 0) {
      unsigned long long* p = &mbits[(size_t)idx * 16 + wave * 4];
      p[0] = b0; p[1] = b1; p[2] = b2; p[3] = b3;
    }
  }
}

// ---- fused QKV projection GEMM: 128x128 tile, BK=32, double-buffered,
// one barrier per iteration; LDS-staged coalesced epilogues.
// V epilogue stores keys PERMUTED within each 16-group (quad 1<->2 swap) so
// the attention PV B-operand slot order matches the S^T C-layout's native
// per-lane key order (no cross-lane P exchange needed in attention). ----
__global__ __launch_bounds__(256) void gemm_qkv_kernel(
    const unsigned short* __restrict__ qb, const unsigned short* __restrict__ kb,
    const unsigned short* __restrict__ vb,
    const unsigned short* __restrict__ wqt, const unsigned short* __restrict__ wkt,
    const unsigned short* __restrict__ wvt,
    const float* __restrict__ bq, const float* __restrict__ bv,
    unsigned short* __restrict__ qh, unsigned short* __restrict__ kh,
    unsigned short* __restrict__ vt) {
  __shared__ unsigned short SB[16640];
  int bid = blockIdx.x;
  int xcd = bid & 7, slot = bid >> 3;      // 96 slots per XCD
  int mi = slot & 3, zn = slot >> 2;       // 4 m-panels per XCD, zn in [0,24)
  int z = zn >> 3;
  int n0 = (zn & 7) * 128;
  int m0 = (mi * 8 + xcd) * 128;
  const unsigned short* A; const unsigned short* Bt;
  switch (z) {
    case 0:  A = qb; Bt = wqt; break;
    case 1:  A = kb; Bt = wkt; break;
    default: A = vb; Bt = wvt; break;
  }
  int t = threadIdx.x, lane = t & 63, wave = t >> 6;
  int l16 = lane & 15, quad = lane >> 4;
  int wm = (wave & 1) * 64, wn = (wave >> 1) * 64;
  f32x4 zero = {0.f, 0.f, 0.f, 0.f};
  f32x4 acc[4][4];
  for (int mt = 0; mt < 4; ++mt) for (int nt = 0; nt < 4; ++nt) acc[mt][nt] = zero;

  int drow = lane >> 2, dcol = (lane & 3) * 8;
  const unsigned short* asrc = A  + (size_t)(m0 + wave * 32 + drow) * D_MODEL + dcol;
  const unsigned short* bsrc = Bt + (size_t)(n0 + wave * 32 + drow) * D_MODEL + dcol;
  int dst = wave * 1024 + lane * 8;        // within-buffer wave slice (+g*512)

#pragma unroll
  for (int g = 0; g < 2; ++g) {
    gll16(asrc + (size_t)(g * 16) * D_MODEL, &SB[dst + g * 512]);
    gll16(bsrc + (size_t)(g * 16) * D_MODEL, &SB[4096 + dst + g * 512]);
  }
  for (int it = 0; it < 32; ++it) {
    __syncthreads();
    if (it + 1 < 32) {
      int nb = ((it + 1) & 1) * 8192, kn = (it + 1) * 32;
#pragma unroll
      for (int g = 0; g < 2; ++g) {
        gll16(asrc + (size_t)(g * 16) * D_MODEL + kn, &SB[nb + dst + g * 512]);
        gll16(bsrc + (size_t)(g * 16) * D_MODEL + kn, &SB[nb + 4096 + dst + g * 512]);
      }
    }
    int cb = (it & 1) * 8192;
    bf16x8 a[4], b[4];
    for (int mt = 0; mt < 4; ++mt)
      a[mt] = *(const bf16x8*)&SB[cb + (wm + mt * 16 + l16) * 32 + quad * 8];
    for (int nt = 0; nt < 4; ++nt)
      b[nt] = *(const bf16x8*)&SB[cb + 4096 + (wn + nt * 16 + l16) * 32 + quad * 8];
    for (int mt = 0; mt < 4; ++mt)
      for (int nt = 0; nt < 4; ++nt)
        acc[mt][nt] = __builtin_amdgcn_mfma_f32_16x16x32_bf16(a[mt], b[nt], acc[mt][nt], 0, 0, 0);
  }

  if (z == 2) {
    __syncthreads();
    // key-permuted store: within each 16-key group, s-position = key with
    // bits 2<->3 swapped == quad 1<->2 swap (self-inverse).
    int qs = ((quad & 1) << 1) | (quad >> 1);
#pragma unroll
    for (int nt = 0; nt < 4; ++nt) {
      int col = wn + nt * 16 + l16;
      float bb = bv[n0 + col];
      for (int mt = 0; mt < 4; ++mt)
        for (int r = 0; r < 4; ++r)
          SB[col * 130 + wm + mt * 16 + qs * 4 + r] = f2b_rhu(acc[mt][nt][r] + bb);
    }
    __syncthreads();
    int c = t >> 1, hf = t & 1;
    int colg = n0 + c, hh = colg >> 6, dd = colg & 63;
    int b_ = m0 >> 11, sbase = m0 & (SEQ - 1);
    unsigned short* dstp = vt + (((size_t)(b_ * NHEAD + hh)) * DK + dd) * SEQ + sbase + hf * 64;
#pragma unroll
    for (int j = 0; j < 8; ++j)
      *(int4*)(dstp + j * 8) = *(const int4*)&SB[c * 130 + hf * 64 + j * 8];
  } else {
    __syncthreads();
#pragma unroll
    for (int nt = 0; nt < 4; ++nt) {
      int lcol = wn + nt * 16 + l16;
      float bb = (z == 0) ? bq[n0 + lcol] : 0.f;
      for (int mt = 0; mt < 4; ++mt)
        for (int r = 0; r < 4; ++r) {
          float val = acc[mt][nt][r] + bb;
          if (z == 0) val *= QSCALE;
          SB[(wm + mt * 16 + quad * 4 + r) * 130 + lcol] = f2b_rhu(val);
        }
    }
    __syncthreads();
    unsigned short* outp = (z == 0) ? qh : kh;
    int b_ = m0 >> 11, sbase = m0 & (SEQ - 1);
    int h0 = n0 >> 6, c = t & 7;
#pragma unroll
    for (int pass = 0; pass < 8; ++pass) {
      int rp = pass * 32 + (t >> 3);
      int srow = rp >> 1, part = rp & 1;
      unsigned short* dstp = outp +
          (((size_t)(b_ * NHEAD + h0 + part)) * SEQ + sbase + srow) * DK + c * 8;
      *(int4*)dstp = *(const int4*)&SB[srow * 130 + part * 64 + c * 8];
    }
  }
}

// ---- output projection GEMM: 64x64 tiles, BK=64 double-buffered ----
__global__ __launch_bounds__(256) void gemm_out_kernel(
    const unsigned short* __restrict__ A, const unsigned short* __restrict__ Bt,
    const float* __restrict__ bias, float* __restrict__ out) {
  __shared__ unsigned short As[8192], Bs[8192];
  int bid = blockIdx.x;
  int xcd = bid & 7, slot = bid >> 3;
  int mi = slot & 7, n0 = (slot >> 3) * 64;
  int m0 = (mi * 8 + xcd) * 64;
  int t = threadIdx.x, lane = t & 63, wave = t >> 6;
  int l16 = lane & 15, quad = lane >> 4;
  int wm = (wave & 1) * 32, wn = (wave >> 1) * 32;
  f32x4 zero = {0.f, 0.f, 0.f, 0.f};
  f32x4 acc[2][2];
  for (int mt = 0; mt < 2; ++mt) for (int nt = 0; nt < 2; ++nt) acc[mt][nt] = zero;

  int drow = lane >> 2, dcol = (lane & 3) * 8;
  const unsigned short* asrc = A  + (size_t)(m0 + wave * 16 + drow) * D_MODEL + dcol;
  const unsigned short* bsrc = Bt + (size_t)(n0 + wave * 16 + drow) * D_MODEL + dcol;
  int dst = wave * 512 + lane * 8;

#pragma unroll
  for (int hf = 0; hf < 2; ++hf) {
    gll16(asrc + hf * 32, &As[dst + hf * 2048]);
    gll16(bsrc + hf * 32, &Bs[dst + hf * 2048]);
  }
  for (int it = 0; it < 16; ++it) {
    __syncthreads();
    if (it + 1 < 16) {
      int nb = ((it + 1) & 1) * 4096, kn = (it + 1) * 64;
#pragma unroll
      for (int hf = 0; hf < 2; ++hf) {
        gll16(asrc + kn + hf * 32, &As[nb + dst + hf * 2048]);
        gll16(bsrc + kn + hf * 32, &Bs[nb + dst + hf * 2048]);
      }
    }
    int cb = (it & 1) * 4096;
#pragma unroll
    for (int half = 0; half < 2; ++half) {
      bf16x8 a[2], b[2];
      for (int mt = 0; mt < 2; ++mt)
        a[mt] = *(const bf16x8*)&As[cb + half * 2048 + (wm + mt * 16 + l16) * 32 + quad * 8];
      for (int nt = 0; nt < 2; ++nt)
        b[nt] = *(const bf16x8*)&Bs[cb + half * 2048 + (wn + nt * 16 + l16) * 32 + quad * 8];
      for (int mt = 0; mt < 2; ++mt)
        for (int nt = 0; nt < 2; ++nt)
          acc[mt][nt] = __builtin_amdgcn_mfma_f32_16x16x32_bf16(a[mt], b[nt], acc[mt][nt], 0, 0, 0);
    }
  }
  for (int nt = 0; nt < 2; ++nt) {
    int col = n0 + wn + nt * 16 + l16;
    float bb = bias[col];
    for (int mt = 0; mt < 2; ++mt)
      for (int r = 0; r < 4; ++r) {
        int row = m0 + wm + mt * 16 + quad * 4 + r;
        out[(size_t)row * D_MODEL + col] = acc[mt][nt][r] + bb;
      }
  }
}

// ---- flash attention R18: KV-SPLIT for occupancy ----
// R8 post-mortem: q-dimension gives exactly 2048 waves = 2/SIMD -- the hard
// occupancy ceiling of every prior geometry. Split the KV stream instead:
// 8-wave blocks = 4 q-subs x 2 kv-groups; group g handles keys
// [128t+64g, 128t+64g+64) each round. Total LDS reads / staged bytes / HBM
// traffic are IDENTICAL (wave-iters conserved: 4096x8 = 2048x16) -- unlike
// R2/R5's occupancy attempts. 16 waves/CU = 4/SIMD. One-time cross-group
// accO/accRS reduction through LDS at the end (~2k cyc). LDS: 2 parity x
// 2 group x (8KB K + 8KB V) = 64KB; 2 blocks/CU. launch_bounds(512,4) pins
// VGPR <= 128 (R7 used 88). All numerics/ops are the R7-proven set.
__global__ __launch_bounds__(512, 4) void attn_kernel(
    const unsigned short* __restrict__ qh, const unsigned short* __restrict__ kh,
    const unsigned short* __restrict__ vt, const unsigned long long* __restrict__ mbits,
    unsigned short* __restrict__ attb) {
  __shared__ unsigned short Ks[16384];  // [par][grp][64 keys][64 d], swizzled
  __shared__ unsigned short Vs[16384];  // [par][grp][64 d][64 s], swizzled
  int bid = blockIdx.x;
  int xcd = bid & 7, slot = bid >> 3;   // 64 slots per XCD
  int bh_ = 4 * xcd + (slot >> 4);      // 4 bh per XCD (KV L2 locality)
  int qt = slot & 15;                   // 16 q-tiles of 128 rows
  int b = bh_ >> 4, h = bh_ & 15;
  int t = threadIdx.x, lane = t & 63, wave = t >> 6;   // 8 waves
  int qsub = wave & 3, grp = wave >> 2;
  int l32 = lane & 31, hi = lane >> 5;
  size_t bh = (size_t)b * NHEAD + h;

  const unsigned short* Kg = kh + bh * SEQ * DK;
  const unsigned short* Vg = vt + bh * DK * SEQ;
  const unsigned long long* mrow = mbits + (size_t)b * SEQ * (SEQ / 64);
  int qrowb = qt * 128 + qsub * 32;     // this wave's 32 q-rows

  // Q fragments (B-operand: col=q=l32, slot (hi,j) -> d = step*16 + hi*8 + j)
  bf16x8 qf[4];
  {
    const unsigned short* Qg = qh + (bh * SEQ + (size_t)(qrowb + l32)) * DK;
#pragma unroll
    for (int step = 0; step < 4; ++step)
      qf[step] = *(const bf16x8*)&Qg[(step * 2 + hi) * 8];
  }

  // staging: one gll16 = 512 thr x 16B = one 64x64 tile. 4 calls/round
  // (K g0, K g1, V g0, V g1). thread -> (row = t>>3, chunk = t&7), source
  // chunk pre-swizzled (^ row&7).
  int srow = t >> 3;
  int schk = ((t & 7) ^ (srow & 7)) * 8;
  const unsigned short* kbase = Kg + (size_t)srow * DK + schk;   // + key0*DK
  const unsigned short* vbase = Vg + (size_t)srow * SEQ + schk;  // + key0
  int sdst = t * 8;                     // within one 4096-short tile

  // K read bases: row = kt2*32 + l32, d-chunk = 2*step + hi, XOR l32&7
  int kx = l32 & 7;
  int kaddr[4];
#pragma unroll
  for (int step = 0; step < 4; ++step)
    kaddr[step] = l32 * 64 + (((step * 2 + hi) ^ kx) * 8);
  // V read: row d = l32 (+32 for accO1), s-chunk = kt2*4 + ks*2 + hi, XOR l32&7

  size_t mi0 = (size_t)(qrowb + l32) * (SEQ / 64);

  bf16x8 ones8;
#pragma unroll
  for (int i = 0; i < 8; ++i) ones8[i] = (short)0x3F80;

  f32x16 zero16;
#pragma unroll
  for (int i = 0; i < 16; ++i) zero16[i] = 0.f;
  f32x16 accO0 = zero16, accO1 = zero16, accRS = zero16;

  // prologue: round 0 -> parity 0
  gll16(kbase, &Ks[sdst]);
  gll16(kbase + (size_t)64 * DK, &Ks[4096 + sdst]);
  gll16(vbase, &Vs[sdst]);
  gll16(vbase + 64, &Vs[4096 + sdst]);

  for (int tr = 0; tr < SEQ / 128; ++tr) {
    __syncthreads();   // drains round tr's DMA (issued a full round ago)
    if (tr + 1 < SEQ / 128) {
      int nb = ((tr + 1) & 1) * 8192;
      size_t k0 = (size_t)(tr + 1) * 128;
      gll16(kbase + k0 * DK, &Ks[nb + sdst]);
      gll16(kbase + (k0 + 64) * DK, &Ks[nb + 4096 + sdst]);
      gll16(vbase + k0, &Vs[nb + sdst]);
      gll16(vbase + k0 + 64, &Vs[nb + 4096 + sdst]);
    }
    // this group's 64-key mask word, issued early (S-MFMA hides latency)
    unsigned long long mw = mrow[mi0 + 2 * tr + grp];

    int tb = (tr & 1) * 8192 + grp * 4096;   // this group's K/V tile base

#pragma unroll
    for (int kt2 = 0; kt2 < 2; ++kt2) {
      // S^T = K . Q^T over 32 keys: lane q=l32, key at regs (r&3)+8(r>>2)+4hi
      f32x16 accS = zero16;
      __builtin_amdgcn_s_setprio(1);
#pragma unroll
      for (int step = 0; step < 4; ++step) {
        bf16x8 kf = *(const bf16x8*)&Ks[tb + kt2 * 2048 + kaddr[step]];
        accS = mfma32(kf, qf[step], accS);
      }
      __builtin_amdgcn_s_setprio(0);

      // masked p = exp2(s) (bit = kt2*32 + 4hi + (r&3)+8*(r>>2))
      unsigned w = (unsigned)(mw >> (kt2 * 32)) >> (4 * hi);
      unsigned pu[16];
#pragma unroll
      for (int r = 0; r < 16; ++r) {
        float pv = __builtin_amdgcn_exp2f(accS[r]);
        const int pos = (r & 3) + 8 * (r >> 2);
        int msk = ((int)(w << (31 - pos))) >> 31;
        pu[r] = __builtin_bit_cast(unsigned, pv) & (unsigned)msk;
      }
      // PV A-frags: OWN regs in order (V global layout is key-permuted to
      // the same slot order via gemm_qkv's quad-swap).
      i32x4 w0v = {pk2u(pu[0], pu[1]),  pk2u(pu[2], pu[3]),
                   pk2u(pu[4], pu[5]),  pk2u(pu[6], pu[7])};    // keys [0,16)
      i32x4 w1v = {pk2u(pu[8], pu[9]),  pk2u(pu[10], pu[11]),
                   pk2u(pu[12], pu[13]), pk2u(pu[14], pu[15])}; // keys [16,32)
      bf16x8 ap0 = __builtin_bit_cast(bf16x8, w0v);
      bf16x8 ap1 = __builtin_bit_cast(bf16x8, w1v);

      __builtin_amdgcn_s_setprio(1);
      accRS = mfma32(ap0, ones8, accRS);
      accRS = mfma32(ap1, ones8, accRS);
      {
        int c0 = ((kt2 * 4 + hi) ^ kx) * 8;        // ks=0 chunk
        int c1 = ((kt2 * 4 + 2 + hi) ^ kx) * 8;    // ks=1 chunk
        bf16x8 vf00 = *(const bf16x8*)&Vs[tb + l32 * 64 + c0];
        bf16x8 vf01 = *(const bf16x8*)&Vs[tb + 2048 + l32 * 64 + c0];
        bf16x8 vf10 = *(const bf16x8*)&Vs[tb + l32 * 64 + c1];
        bf16x8 vf11 = *(const bf16x8*)&Vs[tb + 2048 + l32 * 64 + c1];
        accO0 = mfma32(ap0, vf00, accO0);
        accO1 = mfma32(ap0, vf01, accO1);
        accO0 = mfma32(ap1, vf10, accO0);
        accO1 = mfma32(ap1, vf11, accO1);
      }
      __builtin_amdgcn_s_setprio(0);
    }
  }

  // ---- cross-group reduction (one-time): group 1 -> LDS, group 0 adds ----
  __syncthreads();   // all LDS tile reads done; safe to overwrite
  if (grp == 1) {
    float* redO = (float*)Ks;           // 4 waves x 64 lanes x 32 f32 = 32KB
    float* redR = (float*)Vs;           // 4 waves x 64 lanes x 16 f32 = 16KB
    int ro = (qsub * 64 + lane) * 32;
    int rr = (qsub * 64 + lane) * 16;
#pragma unroll
    for (int r = 0; r < 16; ++r) {
      redO[ro + r] = accO0[r];
      redO[ro + 16 + r] = accO1[r];
      redR[rr + r] = accRS[r];
    }
  }
  __syncthreads();
  if (grp == 0) {
    const float* redO = (const float*)Ks;
    const float* redR = (const float*)Vs;
    int ro = (qsub * 64 + lane) * 32;
    int rr = (qsub * 64 + lane) * 16;
#pragma unroll
    for (int r = 0; r < 16; ++r) {
      accO0[r] += redO[ro + r];
      accO1[r] += redO[ro + 16 + r];
      accRS[r] += redR[rr + r];
    }
    // epilogue: lane holds O[q at regs][d = l32 (+32)]
#pragma unroll
    for (int r = 0; r < 16; ++r) {
      float sden = accRS[r];
      float inv = sden > 0.f ? 1.f / sden : 0.f;
      int qq = (r & 3) + 8 * (r >> 2) + 4 * hi;
      int row = qrowb + qq;
      size_t ob = ((size_t)b * SEQ + row) * D_MODEL + (size_t)h * DK + l32;
      attb[ob] = f2b_rhu(accO0[r] * inv);
      attb[ob + 32] = f2b_rhu(accO1[r] * inv);
    }
  }
}

extern "C" void kernel_launch(void* const* d_in, const int* in_sizes, int n_in,
                              void* d_out, int out_size, void* d_ws, size_t ws_size,
                              hipStream_t stream) {
  (void)in_sizes; (void)n_in; (void)out_size; (void)ws_size;
  const float* q    = (const float*)d_in[0];
  const float* k    = (const float*)d_in[1];
  const float* v    = (const float*)d_in[2];
  const int*   mask = (const int*)d_in[3];
  const float* wq   = (const float*)d_in[4];
  const float* bq   = (const float*)d_in[5];
  const float* wk   = (const float*)d_in[6];
  const float* wv   = (const float*)d_in[7];
  const float* bv   = (const float*)d_in[8];
  const float* wf   = (const float*)d_in[9];
  const float* bf   = (const float*)d_in[10];

  char* ws = (char*)d_ws;
  unsigned short* wft  = (unsigned short*)(ws + 0);          // 2 MiB, live till end
  unsigned short* wqt  = (unsigned short*)(ws + 2097152);    // 2 MiB
  unsigned short* wkt  = (unsigned short*)(ws + 4194304);    // 2 MiB
  unsigned short* wvt  = (unsigned short*)(ws + 6291456);    // 2 MiB
  unsigned short* attb = (unsigned short*)(ws + 2097152);    // 8 MiB alias
  unsigned short* qhp  = (unsigned short*)(ws + 10485760);   // 8 MiB
  unsigned short* khp  = (unsigned short*)(ws + 18874368);   // 8 MiB
  unsigned short* vtp  = (unsigned short*)(ws + 27262976);   // 8 MiB
  unsigned long long* mbits = (unsigned long long*)(ws + 35651584); // 1 MiB
  unsigned short* vb   = (unsigned short*)(ws + 36700160);   // 8 MiB
  unsigned short* qb   = (unsigned short*)d_out;             // 8 MiB (d_out scratch)
  unsigned short* kb   = (unsigned short*)d_out + 4194304;   // 8 MiB

  hipLaunchKernelGGL(prep_kernel, dim3(15360), dim3(256), 0, stream,
                     q, k, v, qb, kb, vb,
                     wq, wk, wv, wf, wqt, wkt, wvt, wft, mask, mbits);
  hipLaunchKernelGGL(gemm_qkv_kernel, dim3(768), dim3(256), 0, stream,
                     qb, kb, vb, wqt, wkt, wvt, bq, bv, qhp, khp, vtp);
  hipLaunchKernelGGL(attn_kernel, dim3(512), dim3(512), 0, stream,
                     qhp, khp, vtp, mbits, attb);
  hipLaunchKernelGGL(gemm_out_kernel, dim3(1024), dim3(256), 0, stream,
                     attb, wft, bf, (float*)d_out);
}